// Round 3
// baseline (8548.465 us; speedup 1.0000x reference)
//
#include <hip/hip_runtime.h>

// TimeLSTM on MI355X (gfx950). B=64,S=1024,D=128,H=256.
// Scan: 64 blocks x 256 threads (4 waves, 1 block/CU, 1 wave/SIMD).
// Thread t owns rows t (f), t+256 (i), t+512 (o), t+768 (c~) of W_all and
// row t of W_d. Weight placement is EXPLICIT (round-2 lesson: 256 arch-VGPR
// ceiling -> scratch spills):
//   VGPR : W_f  chunks 0..31                (128 regs)
//   AGPR : W_i  chunks 0..31, W_o 0..23     (224 regs, inline-asm accvgpr)
//   LDS  : W_o  chunks 24..31, W_d 0..5     (56 KB)
//   L2   : W_c  chunks 0..31, W_d 6..31     (streamed each step, invariant addrs)
// One barrier per step; h/c ping-pong fp16 in LDS (broadcast ds_read_b128).

#define B_ 64
#define S_ 1024
#define D_ 128
#define H_ 256
#define FH_ 1024          // 4H
#define NROWS_ 1280       // 1024 W_all rows + 256 W_d rows

typedef _Float16 half2_t __attribute__((ext_vector_type(2)));
typedef _Float16 half4_t __attribute__((ext_vector_type(4)));
typedef _Float16 half8_t __attribute__((ext_vector_type(8)));
typedef float    f32x4   __attribute__((ext_vector_type(4)));

union HW { half8_t v; half2_t p[4]; int w[4]; };

__device__ inline float dot2acc(half2_t a, half2_t b, float c) {
#if __has_builtin(__builtin_amdgcn_fdot2)
    return __builtin_amdgcn_fdot2(a, b, c, false);
#else
    return c + (float)a[0] * (float)b[0] + (float)a[1] * (float)b[1];
#endif
}

__device__ inline float dot8acc(half8_t a, half8_t b, float c) {
    HW ua; ua.v = a;
    HW ub; ub.v = b;
    c = dot2acc(ua.p[0], ub.p[0], c);
    c = dot2acc(ua.p[1], ub.p[1], c);
    c = dot2acc(ua.p[2], ub.p[2], c);
    c = dot2acc(ua.p[3], ub.p[3], c);
    return c;
}

__device__ inline float sigmoid_f(float x) { return 1.f / (1.f + __expf(-x)); }
__device__ inline float tanh_f(float x)    { return 1.f - 2.f / (__expf(2.f * x) + 1.f); }

#define AGPR_W(dst, src) \
    __asm__ volatile("v_accvgpr_write_b32 %0, %1" : "=a"(dst) : "v"(src))
#define AGPR_R(dst, src) \
    __asm__ volatile("v_accvgpr_read_b32 %0, %1" : "=v"(dst) : "a"(src))

// ---------------------------------------------------------------------------
// Pack: WT fp16 chunk-transposed [32][1280][8]; U16 fp16 row-major [1024][128];
// decay fp32 [64][1024]. Grid 2048 x 256.
// ---------------------------------------------------------------------------
__global__ __launch_bounds__(256) void pack_kernel(
    const float* __restrict__ Wall, const float* __restrict__ Wd,
    const float* __restrict__ Uall, const float* __restrict__ ts,
    _Float16* __restrict__ WT, _Float16* __restrict__ U16,
    float* __restrict__ decay)
{
    int idx = blockIdx.x * 256 + threadIdx.x;
    if (idx < 327680) {
        int r = idx >> 8, c = idx & 255;
        float v = (r < FH_) ? Wall[(size_t)r * H_ + c]
                            : Wd[(size_t)(r - FH_) * H_ + c];
        WT[((size_t)(c >> 3) * NROWS_ + r) * 8 + (c & 7)] = (_Float16)v;
    } else if (idx < 327680 + 131072) {
        int i = idx - 327680;
        U16[i] = (_Float16)Uall[i];
    } else {
        int i = idx - 458752;                // [0, 65536)
        int bb = i >> 10, s = i & 1023;
        float d = 1.f;
        if (s > 0) {
            float dt = ts[bb * S_ + s] - ts[bb * S_ + s - 1];
            dt = fmaxf(dt, 1e-6f);
            d = 1.f / logf(2.718281828459045f + dt);
        }
        decay[i] = d;
    }
}

// ---------------------------------------------------------------------------
// u GEMM via MFMA 16x16x32 f16 (as round 2; validated). Stores u
// gate-interleaved: u16[row][e*4+g], e=element, g=gate.
// ---------------------------------------------------------------------------
__global__ __launch_bounds__(256) void u_gemm_mfma(
    const float* __restrict__ x, const _Float16* __restrict__ U16,
    const float* __restrict__ Ub, _Float16* __restrict__ u16)
{
    int wave = threadIdx.x >> 6, lane = threadIdx.x & 63;
    size_t row0 = (size_t)blockIdx.x * 64 + wave * 16;
    int n0 = blockIdx.y * 256;
    int am = lane & 15;
    int ak = (lane >> 4) * 8;
    const float* xr = x + (row0 + am) * D_ + ak;

    f32x4 acc[16];
    #pragma unroll
    for (int nt = 0; nt < 16; nt++) acc[nt] = (f32x4){0.f, 0.f, 0.f, 0.f};

    #pragma unroll
    for (int kc = 0; kc < 4; kc++) {
        half8_t a;
        #pragma unroll
        for (int e = 0; e < 8; e++) a[e] = (_Float16)xr[kc * 32 + e];
        #pragma unroll
        for (int nt = 0; nt < 16; nt++) {
            half8_t bfr = *(const half8_t*)(U16 + (size_t)(n0 + nt * 16 + am) * D_ + kc * 32 + ak);
            acc[nt] = __builtin_amdgcn_mfma_f32_16x16x32_f16(a, bfr, acc[nt], 0, 0, 0);
        }
    }

    int cr = (lane >> 4) * 4;
    #pragma unroll
    for (int nt = 0; nt < 16; nt++) {
        int col = n0 + nt * 16 + am;
        float bias = Ub[col];
        int e = col & 255, g = col >> 8;
        #pragma unroll
        for (int i = 0; i < 4; i++) {
            u16[(row0 + cr + i) * (size_t)FH_ + e * 4 + g] = (_Float16)(acc[nt][i] + bias);
        }
    }
}

// ---------------------------------------------------------------------------
// Scan.
// ---------------------------------------------------------------------------
__global__ __launch_bounds__(256, 1) void scan_kernel(
    const _Float16* __restrict__ u16, const _Float16* __restrict__ WT,
    const float* __restrict__ Wb, const float* __restrict__ Wdb,
    const float* __restrict__ decay, float* __restrict__ out)
{
    int b = blockIdx.x;
    int t = threadIdx.x;

    __shared__ __align__(16) _Float16 hbuf[2][H_];
    __shared__ __align__(16) _Float16 cbuf[2][H_];
    __shared__ half8_t wlds[14][H_];            // 57344 B: W_o 24..31, W_d 0..5

    const half8_t* __restrict__ WTv = (const half8_t*)WT;

    // ---- VGPR weights: W_f chunks 0..31 ----
    half8_t wf[32];
    #pragma unroll
    for (int cc = 0; cc < 32; cc++) wf[cc] = WTv[(size_t)cc * NROWS_ + t];

    // ---- AGPR weights: W_i 0..31 (128 words), W_o 0..23 (96 words) ----
    int wi_a[128], wo_a[96];
    #pragma unroll
    for (int cc = 0; cc < 32; cc++) {
        HW u_; u_.v = WTv[(size_t)cc * NROWS_ + 256 + t];
        #pragma unroll
        for (int k = 0; k < 4; k++) AGPR_W(wi_a[cc * 4 + k], u_.w[k]);
    }
    #pragma unroll
    for (int cc = 0; cc < 24; cc++) {
        HW u_; u_.v = WTv[(size_t)cc * NROWS_ + 512 + t];
        #pragma unroll
        for (int k = 0; k < 4; k++) AGPR_W(wo_a[cc * 4 + k], u_.w[k]);
    }

    // ---- LDS weights ----
    #pragma unroll
    for (int j = 0; j < 8; j++) wlds[j][t]     = WTv[(size_t)(24 + j) * NROWS_ + 512 + t];
    #pragma unroll
    for (int j = 0; j < 6; j++) wlds[8 + j][t] = WTv[(size_t)j * NROWS_ + FH_ + t];

    float wbf = Wb[t], wbi = Wb[256 + t], wbo = Wb[512 + t], wbc = Wb[768 + t];
    float wdbt = Wdb[t];

    hbuf[0][t] = (_Float16)0.f;
    cbuf[0][t] = (_Float16)0.f;
    float c_reg = 0.f, hn = 0.f;
    __syncthreads();

    const _Float16* __restrict__ ub   = u16 + (size_t)b * S_ * FH_;
    const float*    __restrict__ db   = decay + (size_t)b * S_;
    float*          __restrict__ outb = out + (size_t)b * S_ * H_;

    // loop-invariant streamed-row bases
    const half8_t* __restrict__ wc_base = WTv + 768 + t;   // + cc*NROWS_
    const half8_t* __restrict__ wd_base = WTv + FH_ + t;   // + cc*NROWS_ (cc>=6)

    for (int s = 0; s < S_; s++) {
        int cur = s & 1;
        const half8_t* hc  = (const half8_t*)hbuf[cur];
        const half8_t* cc8 = (const half8_t*)cbuf[cur];

        half4_t u4 = *(const half4_t*)(ub + (size_t)s * FH_ + t * 4);
        float dly = db[s];

        float af = 0.f, ai = 0.f, ao = 0.f, ac = 0.f, ad = 0.f;

        #pragma unroll
        for (int cc = 0; cc < 32; cc++) {
            half8_t h8  = hc[cc];       // LDS broadcast
            half8_t c8v = cc8[cc];      // LDS broadcast

            // f-gate: VGPR
            af = dot8acc(h8, wf[cc], af);

            // i-gate: AGPR
            HW wi;
            AGPR_R(wi.w[0], wi_a[cc * 4 + 0]);
            AGPR_R(wi.w[1], wi_a[cc * 4 + 1]);
            AGPR_R(wi.w[2], wi_a[cc * 4 + 2]);
            AGPR_R(wi.w[3], wi_a[cc * 4 + 3]);
            ai = dot8acc(h8, wi.v, ai);

            // o-gate: AGPR (0..23) or LDS (24..31)
            HW wo;
            if (cc < 24) {
                AGPR_R(wo.w[0], wo_a[cc * 4 + 0]);
                AGPR_R(wo.w[1], wo_a[cc * 4 + 1]);
                AGPR_R(wo.w[2], wo_a[cc * 4 + 2]);
                AGPR_R(wo.w[3], wo_a[cc * 4 + 3]);
            } else {
                wo.v = wlds[cc - 24][t];
            }
            ao = dot8acc(h8, wo.v, ao);

            // c~-gate: streamed from L2 (loop-invariant address)
            half8_t wc = wc_base[(size_t)cc * NROWS_];
            ac = dot8acc(h8, wc, ac);

            // W_d: LDS (0..5) or streamed (6..31); operand is c, not h
            half8_t wd = (cc < 6) ? wlds[8 + cc][t]
                                  : wd_base[(size_t)cc * NROWS_];
            ad = dot8acc(c8v, wd, ad);
        }

        float pf = af + wbf + (float)u4[0];
        float pi = ai + wbi + (float)u4[1];
        float po = ao + wbo + (float)u4[2];
        float pc = ac + wbc + (float)u4[3];

        float cs   = tanh_f(ad + wdbt);
        float cadj = (c_reg - cs) + cs * dly;
        float cn   = sigmoid_f(pf) * cadj + sigmoid_f(pi) * tanh_f(pc);
        hn = sigmoid_f(po) * tanh_f(cn);
        c_reg = cn;

        outb[(size_t)s * H_ + t] = hn;
        int nxt = cur ^ 1;
        hbuf[nxt][t] = (_Float16)hn;
        cbuf[nxt][t] = (_Float16)cn;
        __syncthreads();
    }

    out[(size_t)B_ * S_ * H_ + (size_t)b * H_ + t] = hn;
    out[(size_t)B_ * S_ * H_ + (size_t)B_ * H_ + (size_t)b * H_ + t] = c_reg;
}

// ---------------------------------------------------------------------------
extern "C" void kernel_launch(void* const* d_in, const int* in_sizes, int n_in,
                              void* d_out, int out_size, void* d_ws, size_t ws_size,
                              hipStream_t stream) {
    const float* inputs     = (const float*)d_in[0];   // [B,S,D]
    const float* timestamps = (const float*)d_in[1];   // [B,S]
    const float* W_all_w    = (const float*)d_in[2];   // [4H,H]
    const float* W_all_b    = (const float*)d_in[3];   // [4H]
    const float* U_all_w    = (const float*)d_in[4];   // [4H,D]
    const float* U_all_b    = (const float*)d_in[5];   // [4H]
    const float* W_d_w      = (const float*)d_in[6];   // [H,H]
    const float* W_d_b      = (const float*)d_in[7];   // [H]
    float* out = (float*)d_out;

    char* p = (char*)d_ws;
    _Float16* u16 = (_Float16*)p;                 p += (size_t)B_ * S_ * FH_ * 2;   // 128 MiB
    _Float16* WT  = (_Float16*)p;                 p += (size_t)32 * NROWS_ * 8 * 2; // 640 KiB
    _Float16* U16 = (_Float16*)p;                 p += (size_t)FH_ * D_ * 2;        // 256 KiB
    float*    dec = (float*)p;                                                      // 256 KiB

    pack_kernel<<<dim3(2048), dim3(256), 0, stream>>>(
        W_all_w, W_d_w, U_all_w, timestamps, WT, U16, dec);
    u_gemm_mfma<<<dim3(1024, 4), dim3(256), 0, stream>>>(
        inputs, U16, U_all_b, u16);
    scan_kernel<<<dim3(B_), dim3(256), 0, stream>>>(
        u16, WT, W_all_b, W_d_b, dec, out);
}

// Round 4
// 6333.267 us; speedup vs baseline: 1.3498x; 1.3498x over previous
//
#include <hip/hip_runtime.h>

// TimeLSTM on MI355X (gfx950). B=64,S=1024,D=128,H=256.
// Scan: 64 blocks x 512 threads (8 waves, 2/SIMD). Thread t<256 owns W_all
// rows t (f), 256+t (i) + W_d[t] cols 0..127; t>=256 owns rows 512+e (o),
// 768+e (c~) + W_d[e] cols 128..255 (e=t-256). Per-thread 80 fp16 chunks:
// 36 VGPR + 7 LDS + 37 streamed from L2 (coalesced, double-buffered groups).
// Peak VGPR demand ~250 < 256 (rounds 2/3 died on scratch spills at >256).
// h/c in LDS read as wave-uniform broadcasts (cheap); gate exchange via LDS.

#define B_ 64
#define S_ 1024
#define D_ 128
#define H_ 256
#define FH_ 1024

typedef _Float16 half2_t __attribute__((ext_vector_type(2)));
typedef _Float16 half4_t __attribute__((ext_vector_type(4)));
typedef _Float16 half8_t __attribute__((ext_vector_type(8)));
typedef float    f32x4   __attribute__((ext_vector_type(4)));

union HW { half8_t v; half2_t p[4]; };

__device__ inline float dot2acc(half2_t a, half2_t b, float c) {
#if __has_builtin(__builtin_amdgcn_fdot2)
    return __builtin_amdgcn_fdot2(a, b, c, false);
#else
    return c + (float)a[0] * (float)b[0] + (float)a[1] * (float)b[1];
#endif
}

__device__ inline float dot8acc(half8_t a, half8_t b, float c) {
    HW ua; ua.v = a;
    HW ub; ub.v = b;
    c = dot2acc(ua.p[0], ub.p[0], c);
    c = dot2acc(ua.p[1], ub.p[1], c);
    c = dot2acc(ua.p[2], ub.p[2], c);
    c = dot2acc(ua.p[3], ub.p[3], c);
    return c;
}

__device__ inline float sigmoid_f(float x) { return 1.f / (1.f + __expf(-x)); }
__device__ inline float tanh_f(float x)    { return 1.f - 2.f / (__expf(2.f * x) + 1.f); }

// ---------------------------------------------------------------------------
// Pack. WX slot-major: WX[slot][512 threads][8 halves], slot in [0,80):
//   t<256 (e=t):     slot<32: W_all[e][slot*8..]        (f row)
//                    32..63 : W_all[256+e][(slot-32)*8] (i row)
//                    64..79 : W_d[e][(slot-64)*8]       (cols 0..127)
//   t>=256 (e=t-256):slot<32: W_all[512+e]  (o) ; 32..63: W_all[768+e] (c~)
//                    64..79 : W_d[e][((slot-64)+16)*8]  (cols 128..255)
// Plus U16 (fp16 copy of U_all) and decay. Grid 928 x 256.
// ---------------------------------------------------------------------------
__global__ __launch_bounds__(256) void pack_kernel(
    const float* __restrict__ Wall, const float* __restrict__ Wd,
    const float* __restrict__ Uall, const float* __restrict__ ts,
    _Float16* __restrict__ WX, _Float16* __restrict__ U16,
    float* __restrict__ decay)
{
    int idx = blockIdx.x * 256 + threadIdx.x;
    if (idx < 40960) {
        int slot = idx >> 9, t = idx & 511;
        int e = t & 255, hi = t >> 8;
        int row, ch;
        if (slot < 32)      { row = (hi ? 512 : 0)   + e; ch = slot; }
        else if (slot < 64) { row = (hi ? 768 : 256) + e; ch = slot - 32; }
        else                { row = 1024 + e;             ch = (slot - 64) + (hi ? 16 : 0); }
        const float* src = (row < 1024) ? (Wall + (size_t)row * H_ + ch * 8)
                                        : (Wd + (size_t)(row - 1024) * H_ + ch * 8);
        _Float16* dst = WX + ((size_t)slot * 512 + t) * 8;
        #pragma unroll
        for (int j = 0; j < 8; j++) dst[j] = (_Float16)src[j];
    } else if (idx < 40960 + 131072) {
        int i = idx - 40960;
        U16[i] = (_Float16)Uall[i];
    } else if (idx < 40960 + 131072 + 65536) {
        int i = idx - 172032;                 // [0, 65536)
        int bb = i >> 10, s = i & 1023;
        float d = 1.f;
        if (s > 0) {
            float dt = ts[bb * S_ + s] - ts[bb * S_ + s - 1];
            dt = fmaxf(dt, 1e-6f);
            d = 1.f / logf(2.718281828459045f + dt);
        }
        decay[i] = d;
    }
}

// ---------------------------------------------------------------------------
// u GEMM via MFMA 16x16x32 f16 (validated rounds 2-3). Stores u
// gate-interleaved: u16[row][e*4+g]; dword0 of each half4 = (f,i), dword1 = (o,c~).
// ---------------------------------------------------------------------------
__global__ __launch_bounds__(256) void u_gemm_mfma(
    const float* __restrict__ x, const _Float16* __restrict__ U16,
    const float* __restrict__ Ub, _Float16* __restrict__ u16)
{
    int wave = threadIdx.x >> 6, lane = threadIdx.x & 63;
    size_t row0 = (size_t)blockIdx.x * 64 + wave * 16;
    int n0 = blockIdx.y * 256;
    int am = lane & 15;
    int ak = (lane >> 4) * 8;
    const float* xr = x + (row0 + am) * D_ + ak;

    f32x4 acc[16];
    #pragma unroll
    for (int nt = 0; nt < 16; nt++) acc[nt] = (f32x4){0.f, 0.f, 0.f, 0.f};

    #pragma unroll
    for (int kc = 0; kc < 4; kc++) {
        half8_t a;
        #pragma unroll
        for (int e = 0; e < 8; e++) a[e] = (_Float16)xr[kc * 32 + e];
        #pragma unroll
        for (int nt = 0; nt < 16; nt++) {
            half8_t bfr = *(const half8_t*)(U16 + (size_t)(n0 + nt * 16 + am) * D_ + kc * 32 + ak);
            acc[nt] = __builtin_amdgcn_mfma_f32_16x16x32_f16(a, bfr, acc[nt], 0, 0, 0);
        }
    }

    int cr = (lane >> 4) * 4;
    #pragma unroll
    for (int nt = 0; nt < 16; nt++) {
        int col = n0 + nt * 16 + am;
        float bias = Ub[col];
        int e = col & 255, g = col >> 8;
        #pragma unroll
        for (int i = 0; i < 4; i++) {
            u16[(row0 + cr + i) * (size_t)FH_ + e * 4 + g] = (_Float16)(acc[nt][i] + bias);
        }
    }
}

// ---------------------------------------------------------------------------
// Scan.
// ---------------------------------------------------------------------------
__global__ __launch_bounds__(512, 2) void scan_kernel(
    const _Float16* __restrict__ u16, const _Float16* __restrict__ WX,
    const float* __restrict__ Wb, const float* __restrict__ Wdb,
    const float* __restrict__ decay, float* __restrict__ out)
{
    int b = blockIdx.x, t = threadIdx.x;
    int e = t & 255, hi = t >> 8;

    __shared__ __align__(16) _Float16 h16[H_];
    __shared__ __align__(16) _Float16 c16[H_];
    __shared__ half8_t wl[7][512];             // 57344 B
    __shared__ float po_s[H_], pc_s[H_], adh_s[H_];

    const half8_t* __restrict__ WX8 = (const half8_t*)WX;

    // VGPR weights: slots 0..35 (rowA chunks 0..31, rowB chunks 0..3)
    half8_t wA[32], wB4[4];
    #pragma unroll
    for (int cc = 0; cc < 32; cc++) wA[cc] = WX8[(size_t)cc * 512 + t];
    #pragma unroll
    for (int j = 0; j < 4; j++) wB4[j] = WX8[(size_t)(32 + j) * 512 + t];
    // LDS weights: slots 36..42 (rowB chunks 4..10)
    #pragma unroll
    for (int j = 0; j < 7; j++) wl[j][t] = WX8[(size_t)(36 + j) * 512 + t];

    float bA = Wb[hi * 512 + e];           // f (low) / o (high)
    float bB = Wb[hi * 512 + 256 + e];     // i (low) / c~ (high)
    float wdbt = Wdb[e];

    if (hi == 0) { h16[e] = (_Float16)0.f; c16[e] = (_Float16)0.f; }
    float c_reg = 0.f, hn = 0.f;
    __syncthreads();

    const _Float16* __restrict__ ub   = u16 + (size_t)b * S_ * FH_;
    const float*    __restrict__ db   = decay + (size_t)b * S_;
    float*          __restrict__ outb = out + (size_t)b * S_ * H_;
    const half8_t*  __restrict__ sp   = WX8 + (size_t)43 * 512 + t;  // streamed slots 43..79

    for (int s = 0; s < S_; s++) {
        const half8_t* hb8 = (const half8_t*)h16;
        const half8_t* cb8 = (const half8_t*)c16 + hi * 16;

        half2_t u2 = *(const half2_t*)(ub + (size_t)s * FH_ + e * 4 + hi * 2);

        float aA = 0.f, aB = 0.f, aD = 0.f;

        half8_t s0[8], s1[8];
        #pragma unroll
        for (int j = 0; j < 8; j++) s0[j] = sp[(size_t)j * 512];          // k 0..7

        // chunks 0..10: rowA + rowB(reg 0..3 / lds 4..10)
        #pragma unroll
        for (int cc = 0; cc < 11; cc++) {
            half8_t h8 = hb8[cc];
            aA = dot8acc(h8, wA[cc], aA);
            half8_t wb = (cc < 4) ? wB4[cc] : wl[cc - 4][t];
            aB = dot8acc(h8, wb, aB);
        }
        #pragma unroll
        for (int j = 0; j < 8; j++) s1[j] = sp[(size_t)(8 + j) * 512];    // k 8..15
        #pragma unroll
        for (int j = 0; j < 8; j++) {                                     // chunks 11..18
            int cc = 11 + j; half8_t h8 = hb8[cc];
            aA = dot8acc(h8, wA[cc], aA);
            aB = dot8acc(h8, s0[j], aB);
        }
        #pragma unroll
        for (int j = 0; j < 8; j++) s0[j] = sp[(size_t)(16 + j) * 512];   // k 16..23
        #pragma unroll
        for (int j = 0; j < 8; j++) {                                     // chunks 19..26
            int cc = 19 + j; half8_t h8 = hb8[cc];
            aA = dot8acc(h8, wA[cc], aA);
            aB = dot8acc(h8, s1[j], aB);
        }
        #pragma unroll
        for (int j = 0; j < 8; j++) s1[j] = sp[(size_t)(24 + j) * 512];   // k 24..31
        #pragma unroll
        for (int j = 0; j < 5; j++) {                                     // chunks 27..31
            int cc = 27 + j; half8_t h8 = hb8[cc];
            aA = dot8acc(h8, wA[cc], aA);
            aB = dot8acc(h8, s0[j], aB);
        }
        // W_d: 16 chunks, operand = c. k=21..23 in s0[5..7], k=24..31 in s1, k=32..36 loaded below.
        #pragma unroll
        for (int j = 0; j < 3; j++) aD = dot8acc(cb8[j], s0[5 + j], aD);        // m 0..2
        #pragma unroll
        for (int j = 0; j < 5; j++) s0[j] = sp[(size_t)(32 + j) * 512];   // k 32..36
        #pragma unroll
        for (int j = 0; j < 8; j++) aD = dot8acc(cb8[3 + j], s1[j], aD);        // m 3..10
        #pragma unroll
        for (int j = 0; j < 5; j++) aD = dot8acc(cb8[11 + j], s0[j], aD);       // m 11..15

        float pA = aA + bA + (float)u2[0];
        float pB = aB + bB + (float)u2[1];

        if (hi) {
            po_s[e]  = pA;    // o preact
            pc_s[e]  = pB;    // c~ preact
            adh_s[e] = aD;    // W_d cols 128..255 partial
        }
        __syncthreads();
        if (!hi) {
            float dly  = db[s];
            float cs   = tanh_f(aD + adh_s[e] + wdbt);
            float cadj = (c_reg - cs) + cs * dly;
            float cn   = sigmoid_f(pA) * cadj + sigmoid_f(pB) * tanh_f(pc_s[e]);
            hn = sigmoid_f(po_s[e]) * tanh_f(cn);
            c_reg = cn;
            outb[(size_t)s * H_ + e] = hn;
            h16[e] = (_Float16)hn;
            c16[e] = (_Float16)cn;
        }
        __syncthreads();
    }

    if (!hi) {
        out[(size_t)B_ * S_ * H_ + (size_t)b * H_ + e] = hn;
        out[(size_t)B_ * S_ * H_ + (size_t)B_ * H_ + (size_t)b * H_ + e] = c_reg;
    }
}

// ---------------------------------------------------------------------------
extern "C" void kernel_launch(void* const* d_in, const int* in_sizes, int n_in,
                              void* d_out, int out_size, void* d_ws, size_t ws_size,
                              hipStream_t stream) {
    const float* inputs     = (const float*)d_in[0];   // [B,S,D]
    const float* timestamps = (const float*)d_in[1];   // [B,S]
    const float* W_all_w    = (const float*)d_in[2];   // [4H,H]
    const float* W_all_b    = (const float*)d_in[3];   // [4H]
    const float* U_all_w    = (const float*)d_in[4];   // [4H,D]
    const float* U_all_b    = (const float*)d_in[5];   // [4H]
    const float* W_d_w      = (const float*)d_in[6];   // [H,H]
    const float* W_d_b      = (const float*)d_in[7];   // [H]
    float* out = (float*)d_out;

    char* p = (char*)d_ws;
    _Float16* u16 = (_Float16*)p;   p += (size_t)B_ * S_ * FH_ * 2;   // 128 MiB
    _Float16* WX  = (_Float16*)p;   p += (size_t)80 * 512 * 8 * 2;    // 640 KiB
    _Float16* U16 = (_Float16*)p;   p += (size_t)FH_ * D_ * 2;        // 256 KiB
    float*    dec = (float*)p;                                         // 256 KiB

    pack_kernel<<<dim3(928), dim3(256), 0, stream>>>(
        W_all_w, W_d_w, U_all_w, timestamps, WX, U16, dec);
    u_gemm_mfma<<<dim3(1024, 4), dim3(256), 0, stream>>>(
        inputs, U16, U_all_b, u16);
    scan_kernel<<<dim3(B_), dim3(512), 0, stream>>>(
        u16, WX, W_all_b, W_d_b, dec, out);
}

// Round 5
// 4455.679 us; speedup vs baseline: 1.9186x; 1.4214x over previous
//
#include <hip/hip_runtime.h>

// TimeLSTM on MI355X (gfx950). B=64,S=1024,D=128,H=256.
// Scan: 64 blocks x 512 threads, EXACTLY 2 waves/EU (amdgpu_waves_per_eu(2,2))
// so each wave gets the full 256-VGPR budget -> 8 waves use the whole 512 KB
// register file. Round-4 failure: __launch_bounds__(512,2) let the compiler
// target 4 waves/EU (VGPR=128) and rematerialize "register" weights as per-step
// L2 loads -> 565 KB/step/CU streaming at ~60 B/cyc = 5.9 us/step.
// Thread t<256 owns W_all rows t (f), 256+t (i) + W_d[t] cols 0..127;
// t>=256 owns rows 512+e (o), 768+e (c~) + W_d[e] cols 128..255.
// Per-thread 80 fp16 chunks: 42 VGPR + 17 LDS (dynamic 143 KB) + 21 streamed
// (172 KB/step/CU from L2, double-buffered groups, overlapped).

#define B_ 64
#define S_ 1024
#define D_ 128
#define H_ 256
#define FH_ 1024
#define SMEM_BYTES (4096 + 17 * 512 * 16)   // 143360

typedef _Float16 half2_t __attribute__((ext_vector_type(2)));
typedef _Float16 half4_t __attribute__((ext_vector_type(4)));
typedef _Float16 half8_t __attribute__((ext_vector_type(8)));
typedef float    f32x4   __attribute__((ext_vector_type(4)));

union HW { half8_t v; half2_t p[4]; };

__device__ inline float dot2acc(half2_t a, half2_t b, float c) {
#if __has_builtin(__builtin_amdgcn_fdot2)
    return __builtin_amdgcn_fdot2(a, b, c, false);
#else
    return c + (float)a[0] * (float)b[0] + (float)a[1] * (float)b[1];
#endif
}

__device__ inline float dot8acc(half8_t a, half8_t b, float c) {
    HW ua; ua.v = a;
    HW ub; ub.v = b;
    c = dot2acc(ua.p[0], ub.p[0], c);
    c = dot2acc(ua.p[1], ub.p[1], c);
    c = dot2acc(ua.p[2], ub.p[2], c);
    c = dot2acc(ua.p[3], ub.p[3], c);
    return c;
}

__device__ inline float sigmoid_f(float x) { return 1.f / (1.f + __expf(-x)); }
__device__ inline float tanh_f(float x)    { return 1.f - 2.f / (__expf(2.f * x) + 1.f); }

// ---------------------------------------------------------------------------
// Pack (validated round 4). WX slot-major: WX[slot][512][8], slot in [0,80):
//   slot<32 : rowA chunks (f for t<256, o for t>=256)
//   32..63  : rowB chunks (i / c~)
//   64..79  : W_d[e] chunk (slot-64) + hi*16  (cols 0..127 / 128..255)
// ---------------------------------------------------------------------------
__global__ __launch_bounds__(256) void pack_kernel(
    const float* __restrict__ Wall, const float* __restrict__ Wd,
    const float* __restrict__ Uall, const float* __restrict__ ts,
    _Float16* __restrict__ WX, _Float16* __restrict__ U16,
    float* __restrict__ decay)
{
    int idx = blockIdx.x * 256 + threadIdx.x;
    if (idx < 40960) {
        int slot = idx >> 9, t = idx & 511;
        int e = t & 255, hi = t >> 8;
        int row, ch;
        if (slot < 32)      { row = (hi ? 512 : 0)   + e; ch = slot; }
        else if (slot < 64) { row = (hi ? 768 : 256) + e; ch = slot - 32; }
        else                { row = 1024 + e;             ch = (slot - 64) + (hi ? 16 : 0); }
        const float* src = (row < 1024) ? (Wall + (size_t)row * H_ + ch * 8)
                                        : (Wd + (size_t)(row - 1024) * H_ + ch * 8);
        _Float16* dst = WX + ((size_t)slot * 512 + t) * 8;
        #pragma unroll
        for (int j = 0; j < 8; j++) dst[j] = (_Float16)src[j];
    } else if (idx < 40960 + 131072) {
        int i = idx - 40960;
        U16[i] = (_Float16)Uall[i];
    } else if (idx < 40960 + 131072 + 65536) {
        int i = idx - 172032;
        int bb = i >> 10, s = i & 1023;
        float d = 1.f;
        if (s > 0) {
            float dt = ts[bb * S_ + s] - ts[bb * S_ + s - 1];
            dt = fmaxf(dt, 1e-6f);
            d = 1.f / logf(2.718281828459045f + dt);
        }
        decay[i] = d;
    }
}

// ---------------------------------------------------------------------------
// u GEMM via MFMA 16x16x32 f16 (validated rounds 2-4). Stores u
// gate-interleaved: u16[row][e*4+g], g in {f,i,o,c~}.
// ---------------------------------------------------------------------------
__global__ __launch_bounds__(256) void u_gemm_mfma(
    const float* __restrict__ x, const _Float16* __restrict__ U16,
    const float* __restrict__ Ub, _Float16* __restrict__ u16)
{
    int wave = threadIdx.x >> 6, lane = threadIdx.x & 63;
    size_t row0 = (size_t)blockIdx.x * 64 + wave * 16;
    int n0 = blockIdx.y * 256;
    int am = lane & 15;
    int ak = (lane >> 4) * 8;
    const float* xr = x + (row0 + am) * D_ + ak;

    f32x4 acc[16];
    #pragma unroll
    for (int nt = 0; nt < 16; nt++) acc[nt] = (f32x4){0.f, 0.f, 0.f, 0.f};

    #pragma unroll
    for (int kc = 0; kc < 4; kc++) {
        half8_t a;
        #pragma unroll
        for (int e = 0; e < 8; e++) a[e] = (_Float16)xr[kc * 32 + e];
        #pragma unroll
        for (int nt = 0; nt < 16; nt++) {
            half8_t bfr = *(const half8_t*)(U16 + (size_t)(n0 + nt * 16 + am) * D_ + kc * 32 + ak);
            acc[nt] = __builtin_amdgcn_mfma_f32_16x16x32_f16(a, bfr, acc[nt], 0, 0, 0);
        }
    }

    int cr = (lane >> 4) * 4;
    #pragma unroll
    for (int nt = 0; nt < 16; nt++) {
        int col = n0 + nt * 16 + am;
        float bias = Ub[col];
        int e = col & 255, g = col >> 8;
        #pragma unroll
        for (int i = 0; i < 4; i++) {
            u16[(row0 + cr + i) * (size_t)FH_ + e * 4 + g] = (_Float16)(acc[nt][i] + bias);
        }
    }
}

// ---------------------------------------------------------------------------
// Scan.
// ---------------------------------------------------------------------------
__global__ void __launch_bounds__(512) __attribute__((amdgpu_waves_per_eu(2, 2)))
scan_kernel(
    const _Float16* __restrict__ u16, const _Float16* __restrict__ WX,
    const float* __restrict__ Wb, const float* __restrict__ Wdb,
    const float* __restrict__ decay, float* __restrict__ out)
{
    int b = blockIdx.x, t = threadIdx.x;
    int e = t & 255, hi = t >> 8;

    extern __shared__ __align__(16) char smem[];
    _Float16* h16  = (_Float16*)smem;                 // 512 B
    _Float16* c16  = (_Float16*)(smem + 512);         // 512 B
    float*    po_s = (float*)(smem + 1024);           // 1 KB
    float*    pc_s = (float*)(smem + 2048);           // 1 KB
    float*    adh_s= (float*)(smem + 3072);           // 1 KB
    half8_t*  wl   = (half8_t*)(smem + 4096);         // 17 chunks x 512 thr

    const half8_t* __restrict__ WX8 = (const half8_t*)WX;

    // ---- register weights: rowA chunks 0..31, rowB chunks 0..9 (168 VGPR) ----
    half8_t wA[32], wB[10];
    #pragma unroll
    for (int cc = 0; cc < 32; cc++) wA[cc] = WX8[(size_t)cc * 512 + t];
    #pragma unroll
    for (int j = 0; j < 10; j++) wB[j] = WX8[(size_t)(32 + j) * 512 + t];
    // ---- LDS weights: rowB chunks 10..26 (slots 42..58) ----
    #pragma unroll
    for (int j = 0; j < 17; j++) wl[(size_t)j * 512 + t] = WX8[(size_t)(42 + j) * 512 + t];

    float bA = Wb[hi * 512 + e];           // f / o
    float bB = Wb[hi * 512 + 256 + e];     // i / c~
    float wdbt = Wdb[e];

    if (hi == 0) { h16[e] = (_Float16)0.f; c16[e] = (_Float16)0.f; }
    float c_reg = 0.f, hn = 0.f;
    __syncthreads();

    const _Float16* __restrict__ ub   = u16 + (size_t)b * S_ * FH_;
    const float*    __restrict__ db   = decay + (size_t)b * S_;
    float*          __restrict__ outb = out + (size_t)b * S_ * H_;
    // streamed slots 59..79: rowB 27..31 (5) + W_d 0..15 (16)
    const half8_t*  __restrict__ sp   = WX8 + (size_t)59 * 512 + t;

    const half8_t* hb8 = (const half8_t*)h16;
    const half8_t* cb8 = (const half8_t*)c16 + hi * 16;

    for (int s = 0; s < S_; s++) {
        half2_t u2 = *(const half2_t*)(ub + (size_t)s * FH_ + e * 4 + hi * 2);

        float aA = 0.f, aB = 0.f, aD = 0.f;

        half8_t sB[5], s0[4], s1[4];
        #pragma unroll
        for (int j = 0; j < 5; j++) sB[j] = sp[(size_t)j * 512];          // rowB 27..31
        #pragma unroll
        for (int j = 0; j < 4; j++) s0[j] = sp[(size_t)(5 + j) * 512];    // wd 0..3

        #pragma unroll
        for (int cc = 0; cc < 10; cc++) {
            half8_t h8 = hb8[cc];
            aA = dot8acc(h8, wA[cc], aA);
            aB = dot8acc(h8, wB[cc], aB);
        }
        #pragma unroll
        for (int cc = 10; cc < 27; cc++) {
            half8_t h8 = hb8[cc];
            aA = dot8acc(h8, wA[cc], aA);
            aB = dot8acc(h8, wl[(size_t)(cc - 10) * 512 + t], aB);
        }
        #pragma unroll
        for (int cc = 27; cc < 32; cc++) {
            half8_t h8 = hb8[cc];
            aA = dot8acc(h8, wA[cc], aA);
            aB = dot8acc(h8, sB[cc - 27], aB);
        }

        #pragma unroll
        for (int j = 0; j < 4; j++) s1[j] = sp[(size_t)(9 + j) * 512];    // wd 4..7
        #pragma unroll
        for (int j = 0; j < 4; j++) aD = dot8acc(cb8[j], s0[j], aD);
        #pragma unroll
        for (int j = 0; j < 4; j++) s0[j] = sp[(size_t)(13 + j) * 512];   // wd 8..11
        #pragma unroll
        for (int j = 0; j < 4; j++) aD = dot8acc(cb8[4 + j], s1[j], aD);
        #pragma unroll
        for (int j = 0; j < 4; j++) s1[j] = sp[(size_t)(17 + j) * 512];   // wd 12..15
        #pragma unroll
        for (int j = 0; j < 4; j++) aD = dot8acc(cb8[8 + j], s0[j], aD);
        #pragma unroll
        for (int j = 0; j < 4; j++) aD = dot8acc(cb8[12 + j], s1[j], aD);

        float pA = aA + bA + (float)u2[0];
        float pB = aB + bB + (float)u2[1];

        if (hi) {
            po_s[e]  = pA;
            pc_s[e]  = pB;
            adh_s[e] = aD;
        }
        __syncthreads();
        if (!hi) {
            float dly  = db[s];
            float cs   = tanh_f(aD + adh_s[e] + wdbt);
            float cadj = (c_reg - cs) + cs * dly;
            float cn   = sigmoid_f(pA) * cadj + sigmoid_f(pB) * tanh_f(pc_s[e]);
            hn = sigmoid_f(po_s[e]) * tanh_f(cn);
            c_reg = cn;
            outb[(size_t)s * H_ + e] = hn;
            h16[e] = (_Float16)hn;
            c16[e] = (_Float16)cn;
        }
        __syncthreads();
    }

    if (!hi) {
        out[(size_t)B_ * S_ * H_ + (size_t)b * H_ + e] = hn;
        out[(size_t)B_ * S_ * H_ + (size_t)B_ * H_ + (size_t)b * H_ + e] = c_reg;
    }
}

// ---------------------------------------------------------------------------
extern "C" void kernel_launch(void* const* d_in, const int* in_sizes, int n_in,
                              void* d_out, int out_size, void* d_ws, size_t ws_size,
                              hipStream_t stream) {
    const float* inputs     = (const float*)d_in[0];   // [B,S,D]
    const float* timestamps = (const float*)d_in[1];   // [B,S]
    const float* W_all_w    = (const float*)d_in[2];   // [4H,H]
    const float* W_all_b    = (const float*)d_in[3];   // [4H]
    const float* U_all_w    = (const float*)d_in[4];   // [4H,D]
    const float* U_all_b    = (const float*)d_in[5];   // [4H]
    const float* W_d_w      = (const float*)d_in[6];   // [H,H]
    const float* W_d_b      = (const float*)d_in[7];   // [H]
    float* out = (float*)d_out;

    char* p = (char*)d_ws;
    _Float16* u16 = (_Float16*)p;   p += (size_t)B_ * S_ * FH_ * 2;   // 128 MiB
    _Float16* WX  = (_Float16*)p;   p += (size_t)80 * 512 * 8 * 2;    // 640 KiB
    _Float16* U16 = (_Float16*)p;   p += (size_t)FH_ * D_ * 2;        // 256 KiB
    float*    dec = (float*)p;                                         // 256 KiB

    (void)hipFuncSetAttribute((const void*)scan_kernel,
                              hipFuncAttributeMaxDynamicSharedMemorySize,
                              SMEM_BYTES);

    pack_kernel<<<dim3(928), dim3(256), 0, stream>>>(
        W_all_w, W_d_w, U_all_w, timestamps, WX, U16, dec);
    u_gemm_mfma<<<dim3(1024, 4), dim3(256), 0, stream>>>(
        inputs, U16, U_all_b, u16);
    scan_kernel<<<dim3(B_), dim3(512), SMEM_BYTES, stream>>>(
        u16, WX, W_all_b, W_d_b, dec, out);
}

// Round 6
// 4225.407 us; speedup vs baseline: 2.0231x; 1.0545x over previous
//
#include <hip/hip_runtime.h>

// TimeLSTM on MI355X (gfx950). B=64,S=1024,D=128,H=256.
// Scan: 64 blocks x 512 threads, 2 waves/EU (256-VGPR budget).
// ROUND-5 ROOT CAUSE: weight loads can't be hoisted across the in-loop
// __syncthreads() fence (fence conservatively clobbers memory), so "register"
// weights were re-loaded from L2 every step (VGPR_Count=128, 516 KB/step/CU
// streaming at ~64 B/cyc/CU = 3.4 us/step). FIX: empty inline-asm pins
// (asm("" : "+v"(w))) make the loaded values opaque -> allocator must keep
// them live in VGPRs across the loop.
// Partition per thread (80 chunks): 40 pinned VGPR (160 regs) + 19 LDS
// (159.7 KB dynamic) + 21 streamed from L2 (168 KB/step/CU, 6-deep pipeline).

#define B_ 64
#define S_ 1024
#define D_ 128
#define H_ 256
#define FH_ 1024
#define SMEM_BYTES (4096 + 19 * 512 * 16)   // 159744 <= 160 KiB

typedef _Float16 half2_t __attribute__((ext_vector_type(2)));
typedef _Float16 half4_t __attribute__((ext_vector_type(4)));
typedef _Float16 half8_t __attribute__((ext_vector_type(8)));
typedef float    f32x4   __attribute__((ext_vector_type(4)));

union HW { half8_t v; half2_t p[4]; };

__device__ inline float dot2acc(half2_t a, half2_t b, float c) {
#if __has_builtin(__builtin_amdgcn_fdot2)
    return __builtin_amdgcn_fdot2(a, b, c, false);
#else
    return c + (float)a[0] * (float)b[0] + (float)a[1] * (float)b[1];
#endif
}

__device__ inline float dot8acc(half8_t a, half8_t b, float c) {
    HW ua; ua.v = a;
    HW ub; ub.v = b;
    c = dot2acc(ua.p[0], ub.p[0], c);
    c = dot2acc(ua.p[1], ub.p[1], c);
    c = dot2acc(ua.p[2], ub.p[2], c);
    c = dot2acc(ua.p[3], ub.p[3], c);
    return c;
}

__device__ inline float sigmoid_f(float x) { return 1.f / (1.f + __expf(-x)); }
__device__ inline float tanh_f(float x)    { return 1.f - 2.f / (__expf(2.f * x) + 1.f); }

// ---------------------------------------------------------------------------
// Pack (unchanged, validated). WX slot-major: WX[slot][512][8], slot in [0,80):
//   slot<32 : rowA chunks (f for t<256, o for t>=256)
//   32..63  : rowB chunks (i / c~)
//   64..79  : W_d[e] chunk (slot-64) + hi*16  (cols 0..127 / 128..255)
// ---------------------------------------------------------------------------
__global__ __launch_bounds__(256) void pack_kernel(
    const float* __restrict__ Wall, const float* __restrict__ Wd,
    const float* __restrict__ Uall, const float* __restrict__ ts,
    _Float16* __restrict__ WX, _Float16* __restrict__ U16,
    float* __restrict__ decay)
{
    int idx = blockIdx.x * 256 + threadIdx.x;
    if (idx < 40960) {
        int slot = idx >> 9, t = idx & 511;
        int e = t & 255, hi = t >> 8;
        int row, ch;
        if (slot < 32)      { row = (hi ? 512 : 0)   + e; ch = slot; }
        else if (slot < 64) { row = (hi ? 768 : 256) + e; ch = slot - 32; }
        else                { row = 1024 + e;             ch = (slot - 64) + (hi ? 16 : 0); }
        const float* src = (row < 1024) ? (Wall + (size_t)row * H_ + ch * 8)
                                        : (Wd + (size_t)(row - 1024) * H_ + ch * 8);
        _Float16* dst = WX + ((size_t)slot * 512 + t) * 8;
        #pragma unroll
        for (int j = 0; j < 8; j++) dst[j] = (_Float16)src[j];
    } else if (idx < 40960 + 131072) {
        int i = idx - 40960;
        U16[i] = (_Float16)Uall[i];
    } else if (idx < 40960 + 131072 + 65536) {
        int i = idx - 172032;
        int bb = i >> 10, s = i & 1023;
        float d = 1.f;
        if (s > 0) {
            float dt = ts[bb * S_ + s] - ts[bb * S_ + s - 1];
            dt = fmaxf(dt, 1e-6f);
            d = 1.f / logf(2.718281828459045f + dt);
        }
        decay[i] = d;
    }
}

// ---------------------------------------------------------------------------
// u GEMM via MFMA 16x16x32 f16 (unchanged, validated). Stores u
// gate-interleaved: u16[row][e*4+g], g in {f,i,o,c~}.
// ---------------------------------------------------------------------------
__global__ __launch_bounds__(256) void u_gemm_mfma(
    const float* __restrict__ x, const _Float16* __restrict__ U16,
    const float* __restrict__ Ub, _Float16* __restrict__ u16)
{
    int wave = threadIdx.x >> 6, lane = threadIdx.x & 63;
    size_t row0 = (size_t)blockIdx.x * 64 + wave * 16;
    int n0 = blockIdx.y * 256;
    int am = lane & 15;
    int ak = (lane >> 4) * 8;
    const float* xr = x + (row0 + am) * D_ + ak;

    f32x4 acc[16];
    #pragma unroll
    for (int nt = 0; nt < 16; nt++) acc[nt] = (f32x4){0.f, 0.f, 0.f, 0.f};

    #pragma unroll
    for (int kc = 0; kc < 4; kc++) {
        half8_t a;
        #pragma unroll
        for (int e = 0; e < 8; e++) a[e] = (_Float16)xr[kc * 32 + e];
        #pragma unroll
        for (int nt = 0; nt < 16; nt++) {
            half8_t bfr = *(const half8_t*)(U16 + (size_t)(n0 + nt * 16 + am) * D_ + kc * 32 + ak);
            acc[nt] = __builtin_amdgcn_mfma_f32_16x16x32_f16(a, bfr, acc[nt], 0, 0, 0);
        }
    }

    int cr = (lane >> 4) * 4;
    #pragma unroll
    for (int nt = 0; nt < 16; nt++) {
        int col = n0 + nt * 16 + am;
        float bias = Ub[col];
        int e = col & 255, g = col >> 8;
        #pragma unroll
        for (int i = 0; i < 4; i++) {
            u16[(row0 + cr + i) * (size_t)FH_ + e * 4 + g] = (_Float16)(acc[nt][i] + bias);
        }
    }
}

// ---------------------------------------------------------------------------
// Scan.
// ---------------------------------------------------------------------------
__global__ void __launch_bounds__(512) __attribute__((amdgpu_waves_per_eu(2, 2)))
scan_kernel(
    const _Float16* __restrict__ u16, const _Float16* __restrict__ WX,
    const float* __restrict__ Wb, const float* __restrict__ Wdb,
    const float* __restrict__ decay, float* __restrict__ out)
{
    int b = blockIdx.x, t = threadIdx.x;
    int e = t & 255, hi = t >> 8;

    extern __shared__ __align__(16) char smem[];
    _Float16* h16  = (_Float16*)smem;                 // 512 B
    _Float16* c16  = (_Float16*)(smem + 512);         // 512 B
    float*    po_s = (float*)(smem + 1024);           // 1 KB
    float*    pc_s = (float*)(smem + 2048);           // 1 KB
    float*    adh_s= (float*)(smem + 3072);           // 1 KB
    half8_t*  wl   = (half8_t*)(smem + 4096);         // 19 chunks x 512 thr

    const half8_t* __restrict__ WX8 = (const half8_t*)WX;

    // ---- preload: rowA 0..31 + rowB 0..7 into VGPRs; rowB 8..26 into LDS ----
    half8_t wA[32], wB[8];
    #pragma unroll
    for (int cc = 0; cc < 32; cc++) wA[cc] = WX8[(size_t)cc * 512 + t];
    #pragma unroll
    for (int j = 0; j < 8; j++) wB[j] = WX8[(size_t)(32 + j) * 512 + t];
    #pragma unroll
    for (int j = 0; j < 19; j++) wl[(size_t)j * 512 + t] = WX8[(size_t)(40 + j) * 512 + t];

    // ---- PIN: opaque asm results cannot be rematerialized by reloading,
    //      so these 160 VGPRs stay live across the in-loop barriers. ----
    #pragma unroll
    for (int cc = 0; cc < 32; cc++) asm("" : "+v"(wA[cc]));
    #pragma unroll
    for (int j = 0; j < 8; j++)  asm("" : "+v"(wB[j]));

    float bA = Wb[hi * 512 + e];           // f / o bias
    float bB = Wb[hi * 512 + 256 + e];     // i / c~ bias
    float wdbt = Wdb[e];

    if (hi == 0) { h16[e] = (_Float16)0.f; c16[e] = (_Float16)0.f; }
    float c_reg = 0.f, hn = 0.f;
    __syncthreads();

    const _Float16* __restrict__ ub   = u16 + (size_t)b * S_ * FH_;
    const float*    __restrict__ db   = decay + (size_t)b * S_;
    float*          __restrict__ outb = out + (size_t)b * S_ * H_;
    // streamed slots 59..79: rowB 27..31 (5) + W_d 0..15 (16)
    const half8_t*  __restrict__ sp   = WX8 + (size_t)59 * 512 + t;

    const half8_t* hb8 = (const half8_t*)h16;
    const half8_t* cb8 = (const half8_t*)c16 + hi * 16;

    for (int s = 0; s < S_; s++) {
        half2_t u2 = *(const half2_t*)(ub + (size_t)s * FH_ + e * 4 + hi * 2);

        // rolling 6-deep stream pipeline over 21 chunks
        half8_t sw[6];
        #pragma unroll
        for (int j = 0; j < 6; j++) sw[j] = sp[(size_t)j * 512];

        float aA = 0.f, aB = 0.f, aD = 0.f;

        // pinned-register dots (rowA 0..7 + rowB 0..7)
        #pragma unroll
        for (int cc = 0; cc < 8; cc++) {
            half8_t h8 = hb8[cc];
            aA = dot8acc(h8, wA[cc], aA);
            aB = dot8acc(h8, wB[cc], aB);
        }
        // rowA 8..26 + rowB(LDS) 8..26
        #pragma unroll
        for (int cc = 8; cc < 27; cc++) {
            half8_t h8 = hb8[cc];
            aA = dot8acc(h8, wA[cc], aA);
            aB = dot8acc(h8, wl[(size_t)(cc - 8) * 512 + t], aB);
        }
        // rowA tail 27..31
        #pragma unroll
        for (int cc = 27; cc < 32; cc++) {
            aA = dot8acc(hb8[cc], wA[cc], aA);
        }
        // streamed: rowB 27..31 (with h), then W_d 0..15 (with c)
        #pragma unroll
        for (int i = 0; i < 21; i++) {
            half8_t w = sw[i % 6];
            if (i + 6 < 21) sw[i % 6] = sp[(size_t)(i + 6) * 512];
            if (i < 5) aB = dot8acc(hb8[27 + i], w, aB);
            else       aD = dot8acc(cb8[i - 5], w, aD);
        }

        float pA = aA + bA + (float)u2[0];
        float pB = aB + bB + (float)u2[1];

        if (hi) {
            po_s[e]  = pA;
            pc_s[e]  = pB;
            adh_s[e] = aD;
        }
        __syncthreads();
        if (!hi) {
            float dly  = db[s];
            float cs   = tanh_f(aD + adh_s[e] + wdbt);
            float cadj = (c_reg - cs) + cs * dly;
            float cn   = sigmoid_f(pA) * cadj + sigmoid_f(pB) * tanh_f(pc_s[e]);
            hn = sigmoid_f(po_s[e]) * tanh_f(cn);
            c_reg = cn;
            outb[(size_t)s * H_ + e] = hn;
            h16[e] = (_Float16)hn;
            c16[e] = (_Float16)cn;
        }
        __syncthreads();
    }

    if (!hi) {
        out[(size_t)B_ * S_ * H_ + (size_t)b * H_ + e] = hn;
        out[(size_t)B_ * S_ * H_ + (size_t)B_ * H_ + (size_t)b * H_ + e] = c_reg;
    }
}

// ---------------------------------------------------------------------------
extern "C" void kernel_launch(void* const* d_in, const int* in_sizes, int n_in,
                              void* d_out, int out_size, void* d_ws, size_t ws_size,
                              hipStream_t stream) {
    const float* inputs     = (const float*)d_in[0];   // [B,S,D]
    const float* timestamps = (const float*)d_in[1];   // [B,S]
    const float* W_all_w    = (const float*)d_in[2];   // [4H,H]
    const float* W_all_b    = (const float*)d_in[3];   // [4H]
    const float* U_all_w    = (const float*)d_in[4];   // [4H,D]
    const float* U_all_b    = (const float*)d_in[5];   // [4H]
    const float* W_d_w      = (const float*)d_in[6];   // [H,H]
    const float* W_d_b      = (const float*)d_in[7];   // [H]
    float* out = (float*)d_out;

    char* p = (char*)d_ws;
    _Float16* u16 = (_Float16*)p;   p += (size_t)B_ * S_ * FH_ * 2;   // 128 MiB
    _Float16* WX  = (_Float16*)p;   p += (size_t)80 * 512 * 8 * 2;    // 640 KiB
    _Float16* U16 = (_Float16*)p;   p += (size_t)FH_ * D_ * 2;        // 256 KiB
    float*    dec = (float*)p;                                         // 256 KiB

    (void)hipFuncSetAttribute((const void*)scan_kernel,
                              hipFuncAttributeMaxDynamicSharedMemorySize,
                              SMEM_BYTES);

    pack_kernel<<<dim3(928), dim3(256), 0, stream>>>(
        W_all_w, W_d_w, U_all_w, timestamps, WX, U16, dec);
    u_gemm_mfma<<<dim3(1024, 4), dim3(256), 0, stream>>>(
        inputs, U16, U_all_b, u16);
    scan_kernel<<<dim3(B_), dim3(512), SMEM_BYTES, stream>>>(
        u16, WX, W_all_b, W_d_b, dec, out);
}